// Round 1
// baseline (252.282 us; speedup 1.0000x reference)
//
#include <hip/hip_runtime.h>

#ifndef KE_CONST
#define KE_CONST 14.3996f
#endif

constexpr float LOG2E = 1.4426950408889634f;
constexpr float LN2 = 0.6931471805599453f;

typedef int vint4 __attribute__((ext_vector_type(4)));

// ---- raw-hardware transcendentals (no libm names -> no glibc clash) ----
__device__ __forceinline__ float fast_exp2(float x) { return __builtin_amdgcn_exp2f(x); }
__device__ __forceinline__ float fast_log2(float x) { return __builtin_amdgcn_logf(x); }
__device__ __forceinline__ float fast_exp(float x) { return __builtin_amdgcn_exp2f(x * LOG2E); }
// v_cos_f32: D = cos(S0 * 2*pi) (input in revolutions)
__device__ __forceinline__ float cos_rev(float rev) { return __builtin_amdgcn_cosf(rev); }
__device__ __forceinline__ float fast_sqrt(float x) { return __builtin_amdgcn_sqrtf(x); }
__device__ __forceinline__ float fast_rcp(float x) { return __builtin_amdgcn_rcpf(x); }

__device__ __forceinline__ float softplus_f(float x) {
    return LN2 * fast_log2(1.0f + fast_exp(x));
}

// Force a wave-uniform float into an SGPR (frees a VGPR; legal: value is
// uniform across the wave by construction).
__device__ __forceinline__ float to_sgpr(float x) {
    return __uint_as_float((unsigned)__builtin_amdgcn_readfirstlane((int)__float_as_uint(x)));
}

// Pack per-atom record {x,y,z,Zf} -> one aligned 16B gather; also init out=0
// (d_out is re-poisoned to 0xAA before every timed launch).
__global__ void pack_atoms_kernel(const float* __restrict__ R,
                                  const int* __restrict__ Z,
                                  float4* __restrict__ atoms, int n,
                                  float* __restrict__ out) {
    int t = blockIdx.x * blockDim.x + threadIdx.x;
    if (t == 0) out[0] = 0.0f;
    if (t < n) {
        atoms[t] = make_float4(R[3 * t + 0], R[3 * t + 1], R[3 * t + 2],
                               (float)Z[t]);
    }
}

// 8 edges/thread. Key facts exploited:
//  - atoms table (1.6 MB) >> L1 (32 KB): every gather is a ~200-cycle L2 hit,
//    kernel is latency-bound -> maximize (resident waves) x (loads in flight).
//  - positions ~ N(0,10): ~98% of random pairs have dr^2 >= 36, where the
//    cosine cutoff is EXACTLY 0 in f32 (cos(pi) == -1.0f both in the JAX ref
//    and in v_cos) -> skip the whole transcendental chain for them.
// VGPR budget 84 (launch_bounds 256,6): 64 gather dests + mask + temps fit,
// giving 6 waves/SIMD each with 16 outstanding 16B gathers.
__global__ __launch_bounds__(256, 6) void edge_energy_kernel(
    const int* __restrict__ idx,        // [2*E]
    const float4* __restrict__ atoms,   // packed table
    const float* __restrict__ a_exp, const float* __restrict__ a_num,
    const float* __restrict__ coefficients, const float* __restrict__ exponents,
    const float* __restrict__ rep_scale,
    float* __restrict__ out, int nEdges) {
    __shared__ float zpow_lut[64];
    __shared__ float smem[4];

    // ---- LUT fill (needs only ae), then barrier BEFORE any gathers are
    // issued so no later barrier can force a vmcnt(0) drain mid-flight. ----
    {
        const float ae = softplus_f(a_exp[0]);
        if (threadIdx.x < 64) {
            float z = (float)(threadIdx.x == 0 ? 1 : threadIdx.x);
            zpow_lut[threadIdx.x] = fast_exp2(ae * fast_log2(z));
        }
    }
    __syncthreads();

    const long long tid = (long long)blockIdx.x * blockDim.x + threadIdx.x;
    const long long base = tid * 8;
    const bool full = (base + 8 <= (long long)nEdges);

    float4 A[8], B[8];
    unsigned live = 0;  // bit u: edge u is not a self-edge
    float acc = 0.0f;

    if (full) {
        const vint4* __restrict__ i4 = (const vint4*)(idx) + (base >> 2);
        const vint4* __restrict__ j4 = (const vint4*)(idx + nEdges) + (base >> 2);
        vint4 ia = i4[0];
        vint4 ib = i4[1];
        vint4 ja = j4[0];
        vint4 jb = j4[1];
        int ii[8] = {ia.x, ia.y, ia.z, ia.w, ib.x, ib.y, ib.z, ib.w};
        int jj[8] = {ja.x, ja.y, ja.z, ja.w, jb.x, jb.y, jb.z, jb.w};
        // Compress the self-edge compare into ONE register now so ii/jj die
        // at the gather issue (keeps peak liveness = 64 dests + temps).
#pragma unroll
        for (int u = 0; u < 8; ++u) live |= (ii[u] != jj[u] ? 1u : 0u) << u;
#pragma unroll
        for (int u = 0; u < 8; ++u) {
            A[u] = atoms[ii[u]];
            B[u] = atoms[jj[u]];
        }
        // HARD FENCE: all 16 gathers issued (64 dest VGPRs live) before any
        // compute is scheduled.
        __builtin_amdgcn_sched_barrier(0);
    }

    // ---- Uniform params -> SGPRs, computed in the gathers' latency shadow.
    const float inv_an = to_sgpr(fast_rcp(softplus_f(a_num[0])));
    const float c0 = to_sgpr(softplus_f(coefficients[0]));
    const float c1 = to_sgpr(softplus_f(coefficients[1]));
    const float c2 = to_sgpr(softplus_f(coefficients[2]));
    const float c3 = to_sgpr(softplus_f(coefficients[3]));
    const float e0 = to_sgpr(softplus_f(exponents[0]));
    const float e1 = to_sgpr(softplus_f(exponents[1]));
    const float e2 = to_sgpr(softplus_f(exponents[2]));
    const float e3 = to_sgpr(softplus_f(exponents[3]));
    const float scale = to_sgpr(0.5f * softplus_f(rep_scale[0]) * KE_CONST);

    if (full) {
#pragma unroll
        for (int u = 0; u < 8; ++u) {
            float dx = B[u].x - A[u].x;
            float dy = B[u].y - A[u].y;
            float dz = B[u].z - A[u].z;
            float dr2 = dx * dx + dy * dy + dz * dz;
            // dr^2 >= 36 -> dr clips to 6.0 -> cos cutoff == 0.0f exactly
            // (identical in the reference). Self-edges are masked too.
            if (dr2 < 36.0f && ((live >> u) & 1u)) {
                float dr = fmaxf(fast_sqrt(dr2), 0.02f);
                float cc = 0.5f * (cos_rev(dr * (1.0f / 12.0f)) + 1.0f);
                float zpi = zpow_lut[(int)A[u].w];
                float zpj = zpow_lut[(int)B[u].w];
                float dist = dr * (zpi + zpj) * inv_an;
                float f = c0 * fast_exp(-e0 * dist) + c1 * fast_exp(-e1 * dist) +
                          c2 * fast_exp(-e2 * dist) + c3 * fast_exp(-e3 * dist);
                acc += A[u].w * B[u].w * fast_rcp(dr) * f * cc;
            }
        }
    } else if (base < (long long)nEdges) {
        for (long long t = base; t < (long long)nEdges; ++t) {
            int i = idx[t], j = idx[nEdges + t];
            float4 ai = atoms[i];
            float4 aj = atoms[j];
            float dx = aj.x - ai.x;
            float dy = aj.y - ai.y;
            float dz = aj.z - ai.z;
            float dr2 = dx * dx + dy * dy + dz * dz;
            if (dr2 < 36.0f && i != j) {
                float dr = fmaxf(fast_sqrt(dr2), 0.02f);
                float cc = 0.5f * (cos_rev(dr * (1.0f / 12.0f)) + 1.0f);
                float zpi = zpow_lut[(int)ai.w];
                float zpj = zpow_lut[(int)aj.w];
                float dist = dr * (zpi + zpj) * inv_an;
                float f = c0 * fast_exp(-e0 * dist) + c1 * fast_exp(-e1 * dist) +
                          c2 * fast_exp(-e2 * dist) + c3 * fast_exp(-e3 * dist);
                acc += ai.w * aj.w * fast_rcp(dr) * f * cc;
            }
        }
    }

    // wave(64) shuffle reduce -> block -> one atomic
#pragma unroll
    for (int off = 32; off > 0; off >>= 1) acc += __shfl_down(acc, off, 64);
    const int lane = threadIdx.x & 63;
    const int wave = threadIdx.x >> 6;
    if (lane == 0) smem[wave] = acc;
    __syncthreads();
    if (threadIdx.x == 0) {
        float s = (smem[0] + smem[1]) + (smem[2] + smem[3]);
        atomicAdd(out, s * scale);
    }
}

extern "C" void kernel_launch(void* const* d_in, const int* in_sizes, int n_in,
                              void* d_out, int out_size, void* d_ws, size_t ws_size,
                              hipStream_t stream) {
    // setup_inputs order: R, Z, idx, box, offsets, a_exp, a_num, coefficients,
    //                     exponents, rep_scale
    const float* R = (const float*)d_in[0];
    const int* Z = (const int*)d_in[1];
    const int* idx = (const int*)d_in[2];
    const float* a_exp = (const float*)d_in[5];
    const float* a_num = (const float*)d_in[6];
    const float* coefficients = (const float*)d_in[7];
    const float* exponents = (const float*)d_in[8];
    const float* rep_scale = (const float*)d_in[9];

    const int nAtoms = in_sizes[0] / 3;
    const int nEdges = in_sizes[2] / 2;
    float* out = (float*)d_out;

    float4* atoms = (float4*)d_ws;  // needs nAtoms*16 bytes (1.6 MB @ 100k)
    pack_atoms_kernel<<<(nAtoms + 255) / 256, 256, 0, stream>>>(R, Z, atoms,
                                                                nAtoms, out);
    // 8 edges per thread, exact cover (E = 6.4M -> 3125 blocks of 256)
    const int edges_per_block = 256 * 8;
    const int blocks = (nEdges + edges_per_block - 1) / edges_per_block;
    edge_energy_kernel<<<blocks, 256, 0, stream>>>(
        idx, atoms, a_exp, a_num, coefficients, exponents, rep_scale, out,
        nEdges);
}

// Round 2
// 198.466 us; speedup vs baseline: 1.2712x; 1.2712x over previous
//
#include <hip/hip_runtime.h>

#ifndef KE_CONST
#define KE_CONST 14.3996f
#endif

constexpr float LOG2E = 1.4426950408889634f;
constexpr float LN2 = 0.6931471805599453f;

typedef int vint4 __attribute__((ext_vector_type(4)));

// ---- raw-hardware transcendentals (no libm names -> no glibc clash) ----
__device__ __forceinline__ float fast_exp2(float x) { return __builtin_amdgcn_exp2f(x); }
__device__ __forceinline__ float fast_log2(float x) { return __builtin_amdgcn_logf(x); }
__device__ __forceinline__ float fast_exp(float x) { return __builtin_amdgcn_exp2f(x * LOG2E); }
// v_cos_f32: D = cos(S0 * 2*pi) (input in revolutions)
__device__ __forceinline__ float cos_rev(float rev) { return __builtin_amdgcn_cosf(rev); }
__device__ __forceinline__ float fast_sqrt(float x) { return __builtin_amdgcn_sqrtf(x); }
__device__ __forceinline__ float fast_rcp(float x) { return __builtin_amdgcn_rcpf(x); }

__device__ __forceinline__ float softplus_f(float x) {
    return LN2 * fast_log2(1.0f + fast_exp(x));
}

// Force a wave-uniform float into an SGPR (frees a VGPR; legal: value is
// uniform across the wave by construction).
__device__ __forceinline__ float to_sgpr(float x) {
    return __uint_as_float((unsigned)__builtin_amdgcn_readfirstlane((int)__float_as_uint(x)));
}

// Pack per-atom record {x,y,z,Zf} -> one aligned 16B gather; also init out=0
// (d_out is re-poisoned to 0xAA before every timed launch).
__global__ void pack_atoms_kernel(const float* __restrict__ R,
                                  const int* __restrict__ Z,
                                  float4* __restrict__ atoms, int n,
                                  float* __restrict__ out) {
    int t = blockIdx.x * blockDim.x + threadIdx.x;
    if (t == 0) out[0] = 0.0f;
    if (t < n) {
        atoms[t] = make_float4(R[3 * t + 0], R[3 * t + 1], R[3 * t + 2],
                               (float)Z[t]);
    }
}

// 8 edges/thread, latency-bound on 16 divergent 16B gathers per thread.
// Lessons encoded here:
//  - launch_bounds(256,4): budget 128 VGPRs. (256,6)=84 made the allocator
//    spill A[]/B[] to scratch (200 MB of scratch traffic, 2x slower). Do not
//    lower the budget below the ~100 VGPRs the 16-in-flight pipeline needs.
//  - idx loads issued FIRST; LUT fill + param softplus run in their shadow.
//  - dr^2 >= 36 -> cutoff is EXACTLY 0.0f in f32 (matches JAX ref bit-for-bit,
//    verified absmax==0): ~98% of edges skip the whole transcendental chain,
//    so waves return to the load-issue phase sooner (higher effective MLP).
__global__ __launch_bounds__(256, 4) void edge_energy_kernel(
    const int* __restrict__ idx,        // [2*E]
    const float4* __restrict__ atoms,   // packed table
    const float* __restrict__ a_exp, const float* __restrict__ a_num,
    const float* __restrict__ coefficients, const float* __restrict__ exponents,
    const float* __restrict__ rep_scale,
    float* __restrict__ out, int nEdges) {
    __shared__ float zpow_lut[64];
    __shared__ float smem[4];

    const long long tid = (long long)blockIdx.x * blockDim.x + threadIdx.x;
    const long long base = tid * 8;
    const bool full = (base + 8 <= (long long)nEdges);

    // ---- issue the coalesced idx loads immediately (nothing depends on the
    // preamble); LUT fill + softplus chains execute in their latency shadow.
    vint4 ia, ib, ja, jb;
    if (full) {
        const vint4* __restrict__ i4 = (const vint4*)(idx) + (base >> 2);
        const vint4* __restrict__ j4 = (const vint4*)(idx + nEdges) + (base >> 2);
        ia = i4[0];
        ib = i4[1];
        ja = j4[0];
        jb = j4[1];
    }

    // ---- LUT fill (needs only ae), barrier BEFORE the gathers are issued so
    // no later barrier can force a vmcnt(0) drain mid-flight.
    {
        const float ae = softplus_f(a_exp[0]);
        if (threadIdx.x < 64) {
            float z = (float)(threadIdx.x == 0 ? 1 : threadIdx.x);
            zpow_lut[threadIdx.x] = fast_exp2(ae * fast_log2(z));
        }
    }
    __syncthreads();

    float4 A[8], B[8];
    unsigned live = 0;  // bit u: edge u is not a self-edge
    float acc = 0.0f;

    if (full) {
        int ii[8] = {ia.x, ia.y, ia.z, ia.w, ib.x, ib.y, ib.z, ib.w};
        int jj[8] = {ja.x, ja.y, ja.z, ja.w, jb.x, jb.y, jb.z, jb.w};
#pragma unroll
        for (int u = 0; u < 8; ++u) live |= (ii[u] != jj[u] ? 1u : 0u) << u;
#pragma unroll
        for (int u = 0; u < 8; ++u) {
            A[u] = atoms[ii[u]];
            B[u] = atoms[jj[u]];
        }
        // HARD FENCE: all 16 gathers issued before any compute is scheduled.
        __builtin_amdgcn_sched_barrier(0);
    }

    // ---- Uniform params -> SGPRs, computed while the gathers are in flight.
    const float inv_an = to_sgpr(fast_rcp(softplus_f(a_num[0])));
    const float c0 = to_sgpr(softplus_f(coefficients[0]));
    const float c1 = to_sgpr(softplus_f(coefficients[1]));
    const float c2 = to_sgpr(softplus_f(coefficients[2]));
    const float c3 = to_sgpr(softplus_f(coefficients[3]));
    const float e0 = to_sgpr(softplus_f(exponents[0]));
    const float e1 = to_sgpr(softplus_f(exponents[1]));
    const float e2 = to_sgpr(softplus_f(exponents[2]));
    const float e3 = to_sgpr(softplus_f(exponents[3]));
    const float scale = to_sgpr(0.5f * softplus_f(rep_scale[0]) * KE_CONST);

    if (full) {
#pragma unroll
        for (int u = 0; u < 8; ++u) {
            float dx = B[u].x - A[u].x;
            float dy = B[u].y - A[u].y;
            float dz = B[u].z - A[u].z;
            float dr2 = dx * dx + dy * dy + dz * dz;
            // dr^2 >= 36 -> dr clips to 6.0 -> cos cutoff == 0.0f exactly
            // (identical in the reference). Self-edges masked too.
            if (dr2 < 36.0f && ((live >> u) & 1u)) {
                float dr = fmaxf(fast_sqrt(dr2), 0.02f);
                float cc = 0.5f * (cos_rev(dr * (1.0f / 12.0f)) + 1.0f);
                float zpi = zpow_lut[(int)A[u].w];
                float zpj = zpow_lut[(int)B[u].w];
                float dist = dr * (zpi + zpj) * inv_an;
                float f = c0 * fast_exp(-e0 * dist) + c1 * fast_exp(-e1 * dist) +
                          c2 * fast_exp(-e2 * dist) + c3 * fast_exp(-e3 * dist);
                acc += A[u].w * B[u].w * fast_rcp(dr) * f * cc;
            }
        }
    } else if (base < (long long)nEdges) {
        for (long long t = base; t < (long long)nEdges; ++t) {
            int i = idx[t], j = idx[nEdges + t];
            float4 ai = atoms[i];
            float4 aj = atoms[j];
            float dx = aj.x - ai.x;
            float dy = aj.y - ai.y;
            float dz = aj.z - ai.z;
            float dr2 = dx * dx + dy * dy + dz * dz;
            if (dr2 < 36.0f && i != j) {
                float dr = fmaxf(fast_sqrt(dr2), 0.02f);
                float cc = 0.5f * (cos_rev(dr * (1.0f / 12.0f)) + 1.0f);
                float zpi = zpow_lut[(int)ai.w];
                float zpj = zpow_lut[(int)aj.w];
                float dist = dr * (zpi + zpj) * inv_an;
                float f = c0 * fast_exp(-e0 * dist) + c1 * fast_exp(-e1 * dist) +
                          c2 * fast_exp(-e2 * dist) + c3 * fast_exp(-e3 * dist);
                acc += ai.w * aj.w * fast_rcp(dr) * f * cc;
            }
        }
    }

    // wave(64) shuffle reduce -> block -> one atomic
#pragma unroll
    for (int off = 32; off > 0; off >>= 1) acc += __shfl_down(acc, off, 64);
    const int lane = threadIdx.x & 63;
    const int wave = threadIdx.x >> 6;
    if (lane == 0) smem[wave] = acc;
    __syncthreads();
    if (threadIdx.x == 0) {
        float s = (smem[0] + smem[1]) + (smem[2] + smem[3]);
        atomicAdd(out, s * scale);
    }
}

extern "C" void kernel_launch(void* const* d_in, const int* in_sizes, int n_in,
                              void* d_out, int out_size, void* d_ws, size_t ws_size,
                              hipStream_t stream) {
    // setup_inputs order: R, Z, idx, box, offsets, a_exp, a_num, coefficients,
    //                     exponents, rep_scale
    const float* R = (const float*)d_in[0];
    const int* Z = (const int*)d_in[1];
    const int* idx = (const int*)d_in[2];
    const float* a_exp = (const float*)d_in[5];
    const float* a_num = (const float*)d_in[6];
    const float* coefficients = (const float*)d_in[7];
    const float* exponents = (const float*)d_in[8];
    const float* rep_scale = (const float*)d_in[9];

    const int nAtoms = in_sizes[0] / 3;
    const int nEdges = in_sizes[2] / 2;
    float* out = (float*)d_out;

    float4* atoms = (float4*)d_ws;  // needs nAtoms*16 bytes (1.6 MB @ 100k)
    pack_atoms_kernel<<<(nAtoms + 255) / 256, 256, 0, stream>>>(R, Z, atoms,
                                                                nAtoms, out);
    // 8 edges per thread, exact cover (E = 6.4M -> 3125 blocks of 256)
    const int edges_per_block = 256 * 8;
    const int blocks = (nEdges + edges_per_block - 1) / edges_per_block;
    edge_energy_kernel<<<blocks, 256, 0, stream>>>(
        idx, atoms, a_exp, a_num, coefficients, exponents, rep_scale, out,
        nEdges);
}

// Round 3
// 198.049 us; speedup vs baseline: 1.2738x; 1.0021x over previous
//
#include <hip/hip_runtime.h>

#ifndef KE_CONST
#define KE_CONST 14.3996f
#endif

constexpr float LOG2E = 1.4426950408889634f;
constexpr float LN2 = 0.6931471805599453f;

typedef int vint4 __attribute__((ext_vector_type(4)));

// ---- raw-hardware transcendentals (no libm names -> no glibc clash) ----
__device__ __forceinline__ float fast_exp2(float x) { return __builtin_amdgcn_exp2f(x); }
__device__ __forceinline__ float fast_log2(float x) { return __builtin_amdgcn_logf(x); }
__device__ __forceinline__ float fast_exp(float x) { return __builtin_amdgcn_exp2f(x * LOG2E); }
// v_cos_f32: D = cos(S0 * 2*pi) (input in revolutions)
__device__ __forceinline__ float cos_rev(float rev) { return __builtin_amdgcn_cosf(rev); }
__device__ __forceinline__ float fast_sqrt(float x) { return __builtin_amdgcn_sqrtf(x); }
__device__ __forceinline__ float fast_rcp(float x) { return __builtin_amdgcn_rcpf(x); }

__device__ __forceinline__ float softplus_f(float x) {
    return LN2 * fast_log2(1.0f + fast_exp(x));
}

// Force a wave-uniform float into an SGPR.
__device__ __forceinline__ float to_sgpr(float x) {
    return __uint_as_float((unsigned)__builtin_amdgcn_readfirstlane((int)__float_as_uint(x)));
}

// Pack per-atom record {x,y,z,Zf} -> one aligned 16B gather; also init out=0
// (d_out is re-poisoned to 0xAA before every timed launch).
__global__ void pack_atoms_kernel(const float* __restrict__ R,
                                  const int* __restrict__ Z,
                                  float4* __restrict__ atoms, int n,
                                  float* __restrict__ out) {
    int t = blockIdx.x * blockDim.x + threadIdx.x;
    if (t == 0) out[0] = 0.0f;
    if (t < n) {
        atoms[t] = make_float4(R[3 * t + 0], R[3 * t + 1], R[3 * t + 2],
                               (float)Z[t]);
    }
}

// Persistent-thread edge kernel. History encoded:
//  - r0/r2: one-shot 8-edge waves = 67 us. Compute is fully hidden (early-out
//    bought 0); cost is the divergent-gather memory phase. Per-wave serial
//    phases (idx-load wait ~700cy at birth, teardown) starve the gather issue.
//  - r1: launch_bounds(256,6) spilled A[]/B[] (200 MB scratch, 2x slower).
//    Keep budget 128 (256,4).
//  - This version: grid-stride chunks of 8 edges, idx for chunk n+1
//    double-buffered behind chunk n's gathers; no LDS LUT (z^ae inline on the
//    ~2% surviving path, bit-identical exp2(ae*log2(z))), no top barrier.
__global__ __launch_bounds__(256, 4) void edge_energy_kernel(
    const int* __restrict__ idx,        // [2*E]
    const float4* __restrict__ atoms,   // packed table
    const float* __restrict__ a_exp, const float* __restrict__ a_num,
    const float* __restrict__ coefficients, const float* __restrict__ exponents,
    const float* __restrict__ rep_scale,
    float* __restrict__ out, int nEdges) {
    __shared__ float smem[4];

    const int S = gridDim.x * blockDim.x;  // stride, in chunks
    const int tid = blockIdx.x * blockDim.x + threadIdx.x;
    const int nChunks = nEdges >> 3;

    // ---- uniform params -> SGPRs (one-time; overlaps first idx load) ----
    const float ae     = to_sgpr(softplus_f(a_exp[0]));
    const float inv_an = to_sgpr(fast_rcp(softplus_f(a_num[0])));
    const float c0 = to_sgpr(softplus_f(coefficients[0]));
    const float c1 = to_sgpr(softplus_f(coefficients[1]));
    const float c2 = to_sgpr(softplus_f(coefficients[2]));
    const float c3 = to_sgpr(softplus_f(coefficients[3]));
    const float e0 = to_sgpr(softplus_f(exponents[0]));
    const float e1 = to_sgpr(softplus_f(exponents[1]));
    const float e2 = to_sgpr(softplus_f(exponents[2]));
    const float e3 = to_sgpr(softplus_f(exponents[3]));
    const float scale = to_sgpr(0.5f * softplus_f(rep_scale[0]) * KE_CONST);

    float acc = 0.0f;

    int c = tid;
    vint4 ia, ib, ja, jb;  // idx regs for the CURRENT chunk (prefetched)
    if (c < nChunks) {
        const vint4* __restrict__ i4 = (const vint4*)(idx) + (c << 1);
        const vint4* __restrict__ j4 = (const vint4*)(idx + nEdges) + (c << 1);
        ia = i4[0]; ib = i4[1]; ja = j4[0]; jb = j4[1];
    }

    while (c < nChunks) {
        int ii[8] = {ia.x, ia.y, ia.z, ia.w, ib.x, ib.y, ib.z, ib.w};
        int jj[8] = {ja.x, ja.y, ja.z, ja.w, jb.x, jb.y, jb.z, jb.w};
        unsigned live = 0;
#pragma unroll
        for (int u = 0; u < 8; ++u) live |= (ii[u] != jj[u] ? 1u : 0u) << u;

        float4 A[8], B[8];
#pragma unroll
        for (int u = 0; u < 8; ++u) {
            A[u] = atoms[ii[u]];
            B[u] = atoms[jj[u]];
        }
        // all 16 gathers issued before anything else is scheduled
        __builtin_amdgcn_sched_barrier(0);

        // prefetch idx for the NEXT chunk while the gathers are in flight
        const int cn = c + S;
        if (cn < nChunks) {
            const vint4* __restrict__ i4 = (const vint4*)(idx) + (cn << 1);
            const vint4* __restrict__ j4 = (const vint4*)(idx + nEdges) + (cn << 1);
            ia = i4[0]; ib = i4[1]; ja = j4[0]; jb = j4[1];
        }
        // prefetch issued before compute is scheduled
        __builtin_amdgcn_sched_barrier(0);

#pragma unroll
        for (int u = 0; u < 8; ++u) {
            float dx = B[u].x - A[u].x;
            float dy = B[u].y - A[u].y;
            float dz = B[u].z - A[u].z;
            float dr2 = dx * dx + dy * dy + dz * dz;
            // dr^2 >= 36 -> dr clips to 6.0 -> cutoff == 0.0f exactly (matches
            // the f32 JAX reference; verified absmax==0 in r1/r2).
            if (dr2 < 36.0f && ((live >> u) & 1u)) {
                float dr = fmaxf(fast_sqrt(dr2), 0.02f);
                float cc = 0.5f * (cos_rev(dr * (1.0f / 12.0f)) + 1.0f);
                float zpi = fast_exp2(ae * fast_log2(A[u].w));
                float zpj = fast_exp2(ae * fast_log2(B[u].w));
                float dist = dr * (zpi + zpj) * inv_an;
                float f = c0 * fast_exp(-e0 * dist) + c1 * fast_exp(-e1 * dist) +
                          c2 * fast_exp(-e2 * dist) + c3 * fast_exp(-e3 * dist);
                acc += A[u].w * B[u].w * fast_rcp(dr) * f * cc;
            }
        }
        c = cn;
    }

    // remainder edges (nEdges % 8), scalar on one thread
    if (tid == 0) {
        for (int t = nChunks << 3; t < nEdges; ++t) {
            int i = idx[t], j = idx[nEdges + t];
            float4 ai = atoms[i];
            float4 aj = atoms[j];
            float dx = aj.x - ai.x;
            float dy = aj.y - ai.y;
            float dz = aj.z - ai.z;
            float dr2 = dx * dx + dy * dy + dz * dz;
            if (dr2 < 36.0f && i != j) {
                float dr = fmaxf(fast_sqrt(dr2), 0.02f);
                float cc = 0.5f * (cos_rev(dr * (1.0f / 12.0f)) + 1.0f);
                float zpi = fast_exp2(ae * fast_log2(ai.w));
                float zpj = fast_exp2(ae * fast_log2(aj.w));
                float dist = dr * (zpi + zpj) * inv_an;
                float f = c0 * fast_exp(-e0 * dist) + c1 * fast_exp(-e1 * dist) +
                          c2 * fast_exp(-e2 * dist) + c3 * fast_exp(-e3 * dist);
                acc += ai.w * aj.w * fast_rcp(dr) * f * cc;
            }
        }
    }

    // wave(64) shuffle reduce -> block -> one atomic
#pragma unroll
    for (int off = 32; off > 0; off >>= 1) acc += __shfl_down(acc, off, 64);
    const int lane = threadIdx.x & 63;
    const int wave = threadIdx.x >> 6;
    if (lane == 0) smem[wave] = acc;
    __syncthreads();
    if (threadIdx.x == 0) {
        float s = (smem[0] + smem[1]) + (smem[2] + smem[3]);
        atomicAdd(out, s * scale);
    }
}

extern "C" void kernel_launch(void* const* d_in, const int* in_sizes, int n_in,
                              void* d_out, int out_size, void* d_ws, size_t ws_size,
                              hipStream_t stream) {
    // setup_inputs order: R, Z, idx, box, offsets, a_exp, a_num, coefficients,
    //                     exponents, rep_scale
    const float* R = (const float*)d_in[0];
    const int* Z = (const int*)d_in[1];
    const int* idx = (const int*)d_in[2];
    const float* a_exp = (const float*)d_in[5];
    const float* a_num = (const float*)d_in[6];
    const float* coefficients = (const float*)d_in[7];
    const float* exponents = (const float*)d_in[8];
    const float* rep_scale = (const float*)d_in[9];

    const int nAtoms = in_sizes[0] / 3;
    const int nEdges = in_sizes[2] / 2;
    float* out = (float*)d_out;

    float4* atoms = (float4*)d_ws;  // needs nAtoms*16 bytes (1.6 MB @ 100k)
    pack_atoms_kernel<<<(nAtoms + 255) / 256, 256, 0, stream>>>(R, Z, atoms,
                                                                nAtoms, out);

    // Persistent grid: 4 blocks/CU x 256 CUs at full residency (VGPR<=128).
    // Each thread grid-strides over chunks of 8 edges (~3 iters at E=6.4M),
    // double-buffering the next chunk's idx behind the current gathers.
    const int nChunks = nEdges >> 3;
    int blocks = 1024;
    const int maxNeeded = (nChunks + 255) / 256;
    if (blocks > maxNeeded) blocks = maxNeeded;
    if (blocks < 1) blocks = 1;
    edge_energy_kernel<<<blocks, 256, 0, stream>>>(
        idx, atoms, a_exp, a_num, coefficients, exponents, rep_scale, out,
        nEdges);
}